// Round 15
// baseline (81.906 us; speedup 1.0000x reference)
//
#include <hip/hip_runtime.h>

#define DEV static __device__ __forceinline__

typedef unsigned short u16;
typedef __bf16 bf16_t;
typedef __bf16 bf16x8 __attribute__((ext_vector_type(8)));
typedef float f32x4 __attribute__((ext_vector_type(4)));
typedef u16 u16x8 __attribute__((ext_vector_type(8)));

static constexpr int Bb = 8;     // batch
static constexpr int Nn = 4096;  // tokens per batch
static constexpr int Dd = 256;   // d
static constexpr int DP = 512;   // d_prime

// ---------------- async global->LDS (16B, wave-uniform LDS base + lane*16) ----------------
DEV void gload16(const void* g, void* l) {
  __builtin_amdgcn_global_load_lds(
      (__attribute__((address_space(1))) void*)(unsigned long long)(g),
      (__attribute__((address_space(3))) void*)(unsigned)(unsigned long long)(l),
      16, 0, 0);
}

DEV u16 f2bf(float x) { bf16_t h = (bf16_t)x; return __builtin_bit_cast(u16, h); }
DEV float bf2f(u16 v) { unsigned u = ((unsigned)v) << 16; return __builtin_bit_cast(float, u); }
DEV float gelu_exact(float x) { return 0.5f * x * (1.0f + erff(x * 0.70710678118654752f)); }

// ------- 128 x (NT*32) tile mainloop, TRIPLE-buffered, counted vmcnt (T3/T4-minimum) ------
template <int NT>
DEV void gemm_tile(const u16* Ag, int lda, const u16* Bg, int ldb,
                   int k0, int ksteps, u16* ldsA, u16* ldsB, f32x4 acc[4][NT]) {
  constexpr int BCH  = NT / 2;
  constexpr int ABUF = 4096;
  constexpr int BBUF = NT * 1024;
  const int tid  = threadIdx.x;
  const int wave = tid >> 6, lane = tid & 63;
  const int wr = wave >> 1, wc = wave & 1;
  const int lr = lane & 15, lk = (lane >> 4) * 8;
  const int srow = lane >> 2;
  const int skb  = (lane & 3) * 8;
  const int ca0 = wave * 2, ca1 = ca0 + 1;
  const size_t ga0 = (size_t)(ca0 * 16 + srow) * lda + skb;
  const size_t ga1 = (size_t)(ca1 * 16 + srow) * lda + skb;
  u16* la0 = ldsA + ca0 * 512; u16* la1 = ldsA + ca1 * 512;
  size_t gb[BCH]; u16* lb[BCH];
#pragma unroll
  for (int i = 0; i < BCH; ++i) {
    const int ch = wave * BCH + i;
    gb[i] = (size_t)(ch * 16 + srow) * ldb + skb;
    lb[i] = ldsB + ch * 512;
  }

  auto STAGE = [&](int kt, int buf) {
    const int kk = k0 + kt * 32;
    gload16(Ag + ga0 + kk, la0 + buf * ABUF);
    gload16(Ag + ga1 + kk, la1 + buf * ABUF);
#pragma unroll
    for (int i = 0; i < BCH; ++i) gload16(Bg + gb[i] + kk, lb[i] + buf * BBUF);
  };

  STAGE(0, 0);
  STAGE(1, 1);
  if constexpr (NT == 2) asm volatile("s_waitcnt vmcnt(3)" ::: "memory");
  else                   asm volatile("s_waitcnt vmcnt(4)" ::: "memory");
  __builtin_amdgcn_s_barrier();
  __builtin_amdgcn_sched_barrier(0);

  int cur = 0;
  for (int kt = 0; kt < ksteps; ++kt) {
    const int sb = (cur + 2 >= 3) ? cur - 1 : cur + 2;
    const bool do_stage = (kt + 2 < ksteps);
    if (do_stage) STAGE(kt + 2, sb);
    const u16* pa = ldsA + cur * ABUF;
    const u16* pb = ldsB + cur * BBUF;
    bf16x8 af[4], bfr[NT];
#pragma unroll
    for (int m = 0; m < 4; ++m)
      af[m] = *(const bf16x8*)(pa + (wr * 64 + m * 16 + lr) * 32 + lk);
#pragma unroll
    for (int n = 0; n < NT; ++n)
      bfr[n] = *(const bf16x8*)(pb + (wc * (NT * 16) + n * 16 + lr) * 32 + lk);
#pragma unroll
    for (int m = 0; m < 4; ++m)
#pragma unroll
      for (int n = 0; n < NT; ++n)
        acc[m][n] = __builtin_amdgcn_mfma_f32_16x16x32_bf16(af[m], bfr[n], acc[m][n], 0, 0, 0);
    if (kt + 1 < ksteps) {
      if (do_stage) {
        if constexpr (NT == 2) asm volatile("s_waitcnt vmcnt(3)" ::: "memory");
        else                   asm volatile("s_waitcnt vmcnt(4)" ::: "memory");
      } else {
        asm volatile("s_waitcnt vmcnt(0)" ::: "memory");
      }
      __builtin_amdgcn_s_barrier();
      __builtin_amdgcn_sched_barrier(0);
    }
    cur = (cur + 1 == 3) ? 0 : cur + 1;
  }
  __builtin_amdgcn_s_barrier();
}

template <int NT>
DEV void acc_zero(f32x4 acc[4][NT]) {
#pragma unroll
  for (int m = 0; m < 4; ++m)
#pragma unroll
    for (int n = 0; n < NT; ++n) {
      f32x4 z = {0.f, 0.f, 0.f, 0.f};
      acc[m][n] = z;
    }
}

// ============ S1 mega-kernel: Xp/XpT/s_part (blocks 0..2047) + Wh prep (2048..2143) ========
__global__ __launch_bounds__(256) void k_s1(const float* __restrict__ X, const float* __restrict__ P,
                                            const float* __restrict__ Wh1, const float* __restrict__ Wh2,
                                            u16* __restrict__ Xp, u16* __restrict__ XpT,
                                            float* __restrict__ s_part,
                                            u16* __restrict__ WhT1, u16* __restrict__ Wbf2) {
  __shared__ u16 lt[64 * 65];
  const int bid = blockIdx.x;
  const int t = threadIdx.x;
  if (bid < 2048) {
    const int b  = bid >> 8;
    const int nt = (bid >> 2) & 63;
    const int dt = bid & 3;
    const int n0 = nt * 64, d0 = dt * 64;
    const int r = t >> 2, c0 = (t & 3) * 16;
    const size_t gbase = ((size_t)(b * Nn + n0 + r)) * Dd + d0 + c0;
    u16x8 lo, hi;
#pragma unroll
    for (int i = 0; i < 4; ++i) {
      float4 xv = *(const float4*)(X + gbase + i * 4);
      float4 pv = *(const float4*)(P + gbase + i * 4);
      u16 a0 = f2bf(xv.x + pv.x), a1 = f2bf(xv.y + pv.y);
      u16 a2 = f2bf(xv.z + pv.z), a3 = f2bf(xv.w + pv.w);
      if (i < 2) { lo[i*4+0]=a0; lo[i*4+1]=a1; lo[i*4+2]=a2; lo[i*4+3]=a3; }
      else       { int q=(i-2)*4; hi[q+0]=a0; hi[q+1]=a1; hi[q+2]=a2; hi[q+3]=a3; }
      lt[r * 65 + c0 + i*4 + 0] = a0; lt[r * 65 + c0 + i*4 + 1] = a1;
      lt[r * 65 + c0 + i*4 + 2] = a2; lt[r * 65 + c0 + i*4 + 3] = a3;
    }
    *(u16x8*)(Xp + gbase)     = lo;
    *(u16x8*)(Xp + gbase + 8) = hi;
    __syncthreads();
    const int dd = t >> 2, nc0 = (t & 3) * 16;
    u16x8 olo, ohi;
    float colsum = 0.f;
#pragma unroll
    for (int i = 0; i < 8; ++i) { olo[i] = lt[(nc0 + i) * 65 + dd]; colsum += bf2f(olo[i]); }
#pragma unroll
    for (int i = 0; i < 8; ++i) { ohi[i] = lt[(nc0 + 8 + i) * 65 + dd]; colsum += bf2f(ohi[i]); }
    const size_t obase = ((size_t)(b * Dd + d0 + dd)) * Nn + n0 + nc0;
    *(u16x8*)(XpT + obase)     = olo;
    *(u16x8*)(XpT + obase + 8) = ohi;
    colsum += __shfl_xor(colsum, 1);
    colsum += __shfl_xor(colsum, 2);
    if ((t & 3) == 0) s_part[(size_t)(b * 64 + nt) * Dd + d0 + dd] = colsum;
  } else if (bid < 2048 + 32) {
    const int wb = bid - 2048;
    const int rt = (wb >> 3) & 3;
    const int ct = wb & 7;
    const int r0 = rt * 64, c0t = ct * 64;
    const int r = t >> 2, c0 = (t & 3) * 16;
    const size_t gbase = (size_t)(r0 + r) * DP + c0t + c0;
#pragma unroll
    for (int i = 0; i < 4; ++i) {
      float4 v = *(const float4*)(Wh1 + gbase + i * 4);
      lt[r * 65 + c0 + i*4 + 0] = f2bf(v.x); lt[r * 65 + c0 + i*4 + 1] = f2bf(v.y);
      lt[r * 65 + c0 + i*4 + 2] = f2bf(v.z); lt[r * 65 + c0 + i*4 + 3] = f2bf(v.w);
    }
    __syncthreads();
    const int pp = t >> 2, dc0 = (t & 3) * 16;
    u16x8 olo, ohi;
#pragma unroll
    for (int i = 0; i < 8; ++i) olo[i] = lt[(dc0 + i) * 65 + pp];
#pragma unroll
    for (int i = 0; i < 8; ++i) ohi[i] = lt[(dc0 + 8 + i) * 65 + pp];
    u16* out = WhT1 + (size_t)(c0t + pp) * Dd + r0 + dc0;
    *(u16x8*)(out)     = olo;
    *(u16x8*)(out + 8) = ohi;
  } else {
    const int idx = ((bid - 2048 - 32) * 256 + t) * 8;
    float4 v0 = *(const float4*)(Wh2 + idx);
    float4 v1 = *(const float4*)(Wh2 + idx + 4);
    u16x8 o;
    o[0]=f2bf(v0.x); o[1]=f2bf(v0.y); o[2]=f2bf(v0.z); o[3]=f2bf(v0.w);
    o[4]=f2bf(v1.x); o[5]=f2bf(v1.y); o[6]=f2bf(v1.z); o[7]=f2bf(v1.w);
    *(u16x8*)(Wbf2 + idx) = o;
  }
}

// ====== k_gram: DIRECT full-K — Gb[b][256][256] (bf16) = XpT[b] @ XpT[b]^T over K=4096 ====
// 64 blocks of 128x64 tiles (NT=2): 8b * 2tm * 4tn, XCD-swizzled (batch b -> XCD b; each
// XCD's 8 blocks read one batch's XpT = 2.1 MB, L2-resident). No slabs, no gsum kernel.
__global__ __launch_bounds__(256) void k_gram(const u16* __restrict__ XpT, u16* __restrict__ Gb) {
  __shared__ __align__(16) u16 ldsA[3 * 128 * 32];
  __shared__ __align__(16) u16 ldsB[3 * 64 * 32];
  const int bid0 = blockIdx.x;
  const int bid = (bid0 & 7) * 8 + (bid0 >> 3);    // bijective: 64 = 8 XCD * 8; b = bid>>3
  const int tn = bid & 3;
  const int tm = (bid >> 2) & 1;
  const int b  = bid >> 3;
  const u16* Ag = XpT + (size_t)(b * Dd + tm * 128) * Nn;
  const u16* Bg = XpT + (size_t)(b * Dd + tn * 64) * Nn;
  f32x4 acc[4][2];
  acc_zero<2>(acc);
  gemm_tile<2>(Ag, Nn, Bg, Nn, 0, Nn / 32, ldsA, ldsB, acc);
  const int tid = threadIdx.x, wave = tid >> 6, lane = tid & 63;
  const int wr = wave >> 1, wc = wave & 1, lr = lane & 15, lq = lane >> 4;
  u16* base = Gb + (size_t)(b * Dd + tm * 128) * Dd + tn * 64;
#pragma unroll
  for (int m = 0; m < 4; ++m)
#pragma unroll
    for (int n = 0; n < 2; ++n)
#pragma unroll
      for (int j = 0; j < 4; ++j)
        base[(size_t)(wr * 64 + m * 16 + lq * 4 + j) * Dd + wc * 32 + n * 16 + lr] =
            f2bf(acc[m][n][j]);
}

// ==== k_pmAT: 128 blocks (NT=2): AT[b][d][p] = bf16(gelu(Wh1^T G + bh1 ⊗ s)); c_part ======
// s computed in-block from s_part (prologue). c_part plain stores (summed in k_y).
__global__ __launch_bounds__(256) void k_pmAT(const u16* __restrict__ WhT1, const u16* __restrict__ Gb,
                                              const float* __restrict__ s_part,
                                              const float* __restrict__ bh1, const float* __restrict__ bh2,
                                              u16* __restrict__ AT, float* __restrict__ c_part) {
  __shared__ __align__(16) u16 smem[18432];   // ldsA 3*4096 + ldsB 3*2048; ct (64*136) aliases
  __shared__ float sv[64];
  const int bid = blockIdx.x;        // 8b * 4tm(p) * 4tn(d64)
  const int tn = bid & 3;
  const int tm = (bid >> 2) & 3;
  const int b  = bid >> 4;
  const int p0 = tm * 128, d0 = tn * 64;
  const int tid = threadIdx.x;
  // prologue: sv[j] = sum_nt s_part[b][nt][d0+j]
  if (tid < 64) {
    float sum = 0.f;
#pragma unroll 8
    for (int nt = 0; nt < 64; ++nt) sum += s_part[(size_t)(b * 64 + nt) * Dd + d0 + tid];
    sv[tid] = sum;
  }
  u16* ldsA = smem;
  u16* ldsB = smem + 12288;
  f32x4 acc[4][2];
  acc_zero<2>(acc);
  gemm_tile<2>(WhT1 + (size_t)p0 * Dd, Dd, Gb + (size_t)(b * Dd + d0) * Dd, Dd,
               0, Dd / 32, ldsA, ldsB, acc);
  const int wave = tid >> 6, lane = tid & 63;
  const int wr = wave >> 1, wc = wave & 1, lr = lane & 15, lq = lane >> 4;
  u16* ct = smem;   // aliases gemm bufs (dead after trailing barrier)
#pragma unroll
  for (int n = 0; n < 2; ++n) {
    const int col = wc * 32 + n * 16 + lr;              // d local (0..63)
    const float svv = sv[col];
#pragma unroll
    for (int m = 0; m < 4; ++m)
#pragma unroll
      for (int j = 0; j < 4; ++j) {
        const int row = wr * 64 + m * 16 + lq * 4 + j;  // p local (0..127)
        ct[col * 136 + row] = f2bf(gelu_exact(acc[m][n][j] + bh1[p0 + row] * svv));
      }
  }
  __syncthreads();
#pragma unroll
  for (int it = 0; it < 4; ++it) {
    const int id = tid + it * 256;
    const int dl = id >> 4, ch = id & 15;
    *(u16x8*)(AT + (size_t)(b * Dd + d0 + dl) * DP + p0 + ch * 8) =
        *(const u16x8*)(ct + dl * 136 + ch * 8);
  }
  // c partial over this block's p-range, plain store
  const int ccol = tid >> 2, qtr = tid & 3;
  float csum = 0.f;
#pragma unroll
  for (int q = 0; q < 4; ++q) {
    u16x8 av = *(const u16x8*)(ct + ccol * 136 + qtr * 32 + q * 8);
#pragma unroll
    for (int i = 0; i < 8; ++i) csum += bh2[p0 + qtr * 32 + q * 8 + i] * bf2f(av[i]);
  }
  csum += __shfl_xor(csum, 1);
  csum += __shfl_xor(csum, 2);
  if (qtr == 0) c_part[(size_t)(b * 4 + tm) * Dd + d0 + ccol] = csum;
}

// ---------------- k_h: 64 blocks (NT=2): HT[b][d_out][kd] = bf16(Wh2 @ A)^T ---------------
__global__ __launch_bounds__(256) void k_h(const u16* __restrict__ Wbf2, const u16* __restrict__ AT,
                                           u16* __restrict__ HT) {
  __shared__ __align__(16) u16 smem[18432];
  u16* ldsA = smem;
  u16* ldsB = smem + 12288;
  u16* ct   = smem;
  const int bid = blockIdx.x;        // 8b * 2tm(kd) * 4tn(d64)
  const int tn = bid & 3;
  const int tm = (bid >> 2) & 1;
  const int b  = bid >> 3;
  const int k0 = tm * 128, d0 = tn * 64;
  f32x4 acc[4][2];
  acc_zero<2>(acc);
  gemm_tile<2>(Wbf2 + (size_t)k0 * DP, DP, AT + (size_t)(b * Dd + d0) * DP, DP,
               0, DP / 32, ldsA, ldsB, acc);
  const int tid = threadIdx.x, wave = tid >> 6, lane = tid & 63;
  const int wr = wave >> 1, wc = wave & 1, lr = lane & 15, lq = lane >> 4;
#pragma unroll
  for (int n = 0; n < 2; ++n) {
    const int col = wc * 32 + n * 16 + lr;              // d_out local (0..63)
#pragma unroll
    for (int m = 0; m < 4; ++m)
#pragma unroll
      for (int j = 0; j < 4; ++j)
        ct[col * 136 + wr * 64 + m * 16 + lq * 4 + j] = f2bf(acc[m][n][j]);
  }
  __syncthreads();
#pragma unroll
  for (int it = 0; it < 4; ++it) {
    const int id = tid + it * 256;
    const int dl = id >> 4, ch = id & 15;
    *(u16x8*)(HT + (size_t)(b * Dd + d0 + dl) * Dd + k0 + ch * 8) =
        *(const u16x8*)(ct + dl * 136 + ch * 8);
  }
}

// -------- k_y: Y[b][n][d] = Xp[b] @ H[b] + sum_tm c_part  (1024 blocks of 128x64, NT=2) ---
__global__ __launch_bounds__(256) void k_y(const u16* __restrict__ Xp, const u16* __restrict__ HT,
                                           const float* __restrict__ c_part, float* __restrict__ Y) {
  __shared__ __align__(16) u16 ldsA[3 * 128 * 32];
  __shared__ __align__(16) u16 ldsB[3 * 64 * 32];
  const int bid0 = blockIdx.x;
  const int bid = (bid0 & 7) * 128 + (bid0 >> 3);   // bijective: 1024 = 8 XCD * 128
  const int b  = bid >> 7;
  const int tm = (bid >> 2) & 31;
  const int tn = bid & 3;
  const u16* Ag = Xp + (size_t)(b * Nn + tm * 128) * Dd;
  const u16* Bg = HT + (size_t)(b * Dd + tn * 64) * Dd;
  f32x4 acc[4][2];
  acc_zero<2>(acc);
  gemm_tile<2>(Ag, Dd, Bg, Dd, 0, Dd / 32, ldsA, ldsB, acc);
  const int tid = threadIdx.x, wave = tid >> 6, lane = tid & 63;
  const int wr = wave >> 1, wc = wave & 1, lr = lane & 15, lq = lane >> 4;
  float* base = Y + (size_t)(b * Nn + tm * 128) * Dd + tn * 64;
#pragma unroll
  for (int n = 0; n < 2; ++n) {
    const int col = wc * 32 + n * 16 + lr;
    const int gcol = tn * 64 + col;
    const float cv = c_part[(size_t)(b * 4 + 0) * Dd + gcol] + c_part[(size_t)(b * 4 + 1) * Dd + gcol]
                   + c_part[(size_t)(b * 4 + 2) * Dd + gcol] + c_part[(size_t)(b * 4 + 3) * Dd + gcol];
#pragma unroll
    for (int m = 0; m < 4; ++m)
#pragma unroll
      for (int j = 0; j < 4; ++j)
        base[(size_t)(wr * 64 + m * 16 + lq * 4 + j) * Dd + col] = acc[m][n][j] + cv;
  }
}

// ---------------- launcher ----------------
extern "C" void kernel_launch(void* const* d_in, const int* in_sizes, int n_in,
                              void* d_out, int out_size, void* d_ws, size_t ws_size,
                              hipStream_t stream) {
  const float* X   = (const float*)d_in[0];
  const float* P   = (const float*)d_in[1];
  const float* Wh1 = (const float*)d_in[2];
  const float* bh1 = (const float*)d_in[3];
  const float* Wh2 = (const float*)d_in[4];
  const float* bh2 = (const float*)d_in[5];
  float* Y = (float*)d_out;
  char* ws = (char*)d_ws;

  // workspace layout (bytes)
  u16*   Xp     = (u16*)(ws);                     // 16,777,216
  u16*   XpT    = (u16*)(ws + 16777216);          // 16,777,216
  u16*   WhT1   = (u16*)(ws + 33554432);          //    262,144
  u16*   Wbf2   = (u16*)(ws + 33816576);          //    262,144
  float* s_part = (float*)(ws + 34078720);        //    524,288
  float* c_part = (float*)(ws + 34603008);        //     32,768
  u16*   Gb     = (u16*)(ws + 34635776);          //  1,048,576
  u16*   AT     = (u16*)(ws + 35684352);          //  2,097,152
  u16*   HT     = (u16*)(ws + 37781504);          //  1,048,576
  const size_t WS_NEED = 38830080;
  if (ws_size < WS_NEED) return;

  k_s1  <<<2144, 256, 0, stream>>>(X, P, Wh1, Wh2, Xp, XpT, s_part, WhT1, Wbf2);
  k_gram<<<64,   256, 0, stream>>>(XpT, Gb);
  k_pmAT<<<128,  256, 0, stream>>>(WhT1, Gb, s_part, bh1, bh2, AT, c_part);
  k_h   <<<64,   256, 0, stream>>>(Wbf2, AT, HT);
  k_y   <<<1024, 256, 0, stream>>>(Xp, HT, c_part, Y);
}

// Round 17
// 62.658 us; speedup vs baseline: 1.3072x; 1.3072x over previous
//
#include <hip/hip_runtime.h>

#define DEV static __device__ __forceinline__

typedef unsigned short u16;
typedef __bf16 bf16_t;
typedef __bf16 bf16x8 __attribute__((ext_vector_type(8)));
typedef float f32x4 __attribute__((ext_vector_type(4)));
typedef u16 u16x8 __attribute__((ext_vector_type(8)));

static constexpr int Bb = 8;     // batch
static constexpr int Nn = 4096;  // tokens per batch
static constexpr int Dd = 256;   // d
static constexpr int DP = 512;   // d_prime

// ---------------- async global->LDS (16B, wave-uniform LDS base + lane*16) ----------------
DEV void gload16(const void* g, void* l) {
  __builtin_amdgcn_global_load_lds(
      (__attribute__((address_space(1))) void*)(unsigned long long)(g),
      (__attribute__((address_space(3))) void*)(unsigned)(unsigned long long)(l),
      16, 0, 0);
}

DEV u16 f2bf(float x) { bf16_t h = (bf16_t)x; return __builtin_bit_cast(u16, h); }
DEV float bf2f(u16 v) { unsigned u = ((unsigned)v) << 16; return __builtin_bit_cast(float, u); }
DEV float gelu_exact(float x) { return 0.5f * x * (1.0f + erff(x * 0.70710678118654752f)); }

// ------- 128 x (NT*32) tile mainloop, TRIPLE-buffered, counted vmcnt (T3/T4-minimum) ------
template <int NT>
DEV void gemm_tile(const u16* Ag, int lda, const u16* Bg, int ldb,
                   int k0, int ksteps, u16* ldsA, u16* ldsB, f32x4 acc[4][NT]) {
  constexpr int BCH  = NT / 2;
  constexpr int ABUF = 4096;
  constexpr int BBUF = NT * 1024;
  const int tid  = threadIdx.x;
  const int wave = tid >> 6, lane = tid & 63;
  const int wr = wave >> 1, wc = wave & 1;
  const int lr = lane & 15, lk = (lane >> 4) * 8;
  const int srow = lane >> 2;
  const int skb  = (lane & 3) * 8;
  const int ca0 = wave * 2, ca1 = ca0 + 1;
  const size_t ga0 = (size_t)(ca0 * 16 + srow) * lda + skb;
  const size_t ga1 = (size_t)(ca1 * 16 + srow) * lda + skb;
  u16* la0 = ldsA + ca0 * 512; u16* la1 = ldsA + ca1 * 512;
  size_t gb[BCH]; u16* lb[BCH];
#pragma unroll
  for (int i = 0; i < BCH; ++i) {
    const int ch = wave * BCH + i;
    gb[i] = (size_t)(ch * 16 + srow) * ldb + skb;
    lb[i] = ldsB + ch * 512;
  }

  auto STAGE = [&](int kt, int buf) {
    const int kk = k0 + kt * 32;
    gload16(Ag + ga0 + kk, la0 + buf * ABUF);
    gload16(Ag + ga1 + kk, la1 + buf * ABUF);
#pragma unroll
    for (int i = 0; i < BCH; ++i) gload16(Bg + gb[i] + kk, lb[i] + buf * BBUF);
  };

  STAGE(0, 0);
  STAGE(1, 1);
  if constexpr (NT == 2) asm volatile("s_waitcnt vmcnt(3)" ::: "memory");
  else                   asm volatile("s_waitcnt vmcnt(4)" ::: "memory");
  __builtin_amdgcn_s_barrier();
  __builtin_amdgcn_sched_barrier(0);

  int cur = 0;
  for (int kt = 0; kt < ksteps; ++kt) {
    const int sb = (cur + 2 >= 3) ? cur - 1 : cur + 2;
    const bool do_stage = (kt + 2 < ksteps);
    if (do_stage) STAGE(kt + 2, sb);
    const u16* pa = ldsA + cur * ABUF;
    const u16* pb = ldsB + cur * BBUF;
    bf16x8 af[4], bfr[NT];
#pragma unroll
    for (int m = 0; m < 4; ++m)
      af[m] = *(const bf16x8*)(pa + (wr * 64 + m * 16 + lr) * 32 + lk);
#pragma unroll
    for (int n = 0; n < NT; ++n)
      bfr[n] = *(const bf16x8*)(pb + (wc * (NT * 16) + n * 16 + lr) * 32 + lk);
#pragma unroll
    for (int m = 0; m < 4; ++m)
#pragma unroll
      for (int n = 0; n < NT; ++n)
        acc[m][n] = __builtin_amdgcn_mfma_f32_16x16x32_bf16(af[m], bfr[n], acc[m][n], 0, 0, 0);
    if (kt + 1 < ksteps) {
      if (do_stage) {
        if constexpr (NT == 2) asm volatile("s_waitcnt vmcnt(3)" ::: "memory");
        else                   asm volatile("s_waitcnt vmcnt(4)" ::: "memory");
      } else {
        asm volatile("s_waitcnt vmcnt(0)" ::: "memory");
      }
      __builtin_amdgcn_s_barrier();
      __builtin_amdgcn_sched_barrier(0);
    }
    cur = (cur + 1 == 3) ? 0 : cur + 1;
  }
  __builtin_amdgcn_s_barrier();
}

template <int NT>
DEV void acc_zero(f32x4 acc[4][NT]) {
#pragma unroll
  for (int m = 0; m < 4; ++m)
#pragma unroll
    for (int n = 0; n < NT; ++n) {
      f32x4 z = {0.f, 0.f, 0.f, 0.f};
      acc[m][n] = z;
    }
}

// ============ S1 mega-kernel: Xp/XpT/s_part (blocks 0..2047) + Wh prep (2048..2143) ========
__global__ __launch_bounds__(256) void k_s1(const float* __restrict__ X, const float* __restrict__ P,
                                            const float* __restrict__ Wh1, const float* __restrict__ Wh2,
                                            u16* __restrict__ Xp, u16* __restrict__ XpT,
                                            float* __restrict__ s_part,
                                            u16* __restrict__ WhT1, u16* __restrict__ Wbf2) {
  __shared__ u16 lt[64 * 65];
  const int bid = blockIdx.x;
  const int t = threadIdx.x;
  if (bid < 2048) {
    const int b  = bid >> 8;
    const int nt = (bid >> 2) & 63;
    const int dt = bid & 3;
    const int n0 = nt * 64, d0 = dt * 64;
    const int r = t >> 2, c0 = (t & 3) * 16;
    const size_t gbase = ((size_t)(b * Nn + n0 + r)) * Dd + d0 + c0;
    u16x8 lo, hi;
#pragma unroll
    for (int i = 0; i < 4; ++i) {
      float4 xv = *(const float4*)(X + gbase + i * 4);
      float4 pv = *(const float4*)(P + gbase + i * 4);
      u16 a0 = f2bf(xv.x + pv.x), a1 = f2bf(xv.y + pv.y);
      u16 a2 = f2bf(xv.z + pv.z), a3 = f2bf(xv.w + pv.w);
      if (i < 2) { lo[i*4+0]=a0; lo[i*4+1]=a1; lo[i*4+2]=a2; lo[i*4+3]=a3; }
      else       { int q=(i-2)*4; hi[q+0]=a0; hi[q+1]=a1; hi[q+2]=a2; hi[q+3]=a3; }
      lt[r * 65 + c0 + i*4 + 0] = a0; lt[r * 65 + c0 + i*4 + 1] = a1;
      lt[r * 65 + c0 + i*4 + 2] = a2; lt[r * 65 + c0 + i*4 + 3] = a3;
    }
    *(u16x8*)(Xp + gbase)     = lo;
    *(u16x8*)(Xp + gbase + 8) = hi;
    __syncthreads();
    const int dd = t >> 2, nc0 = (t & 3) * 16;
    u16x8 olo, ohi;
    float colsum = 0.f;
#pragma unroll
    for (int i = 0; i < 8; ++i) { olo[i] = lt[(nc0 + i) * 65 + dd]; colsum += bf2f(olo[i]); }
#pragma unroll
    for (int i = 0; i < 8; ++i) { ohi[i] = lt[(nc0 + 8 + i) * 65 + dd]; colsum += bf2f(ohi[i]); }
    const size_t obase = ((size_t)(b * Dd + d0 + dd)) * Nn + n0 + nc0;
    *(u16x8*)(XpT + obase)     = olo;
    *(u16x8*)(XpT + obase + 8) = ohi;
    colsum += __shfl_xor(colsum, 1);
    colsum += __shfl_xor(colsum, 2);
    if ((t & 3) == 0) s_part[(size_t)(b * 64 + nt) * Dd + d0 + dd] = colsum;
  } else if (bid < 2048 + 32) {
    const int wb = bid - 2048;
    const int rt = (wb >> 3) & 3;
    const int ct = wb & 7;
    const int r0 = rt * 64, c0t = ct * 64;
    const int r = t >> 2, c0 = (t & 3) * 16;
    const size_t gbase = (size_t)(r0 + r) * DP + c0t + c0;
#pragma unroll
    for (int i = 0; i < 4; ++i) {
      float4 v = *(const float4*)(Wh1 + gbase + i * 4);
      lt[r * 65 + c0 + i*4 + 0] = f2bf(v.x); lt[r * 65 + c0 + i*4 + 1] = f2bf(v.y);
      lt[r * 65 + c0 + i*4 + 2] = f2bf(v.z); lt[r * 65 + c0 + i*4 + 3] = f2bf(v.w);
    }
    __syncthreads();
    const int pp = t >> 2, dc0 = (t & 3) * 16;
    u16x8 olo, ohi;
#pragma unroll
    for (int i = 0; i < 8; ++i) olo[i] = lt[(dc0 + i) * 65 + pp];
#pragma unroll
    for (int i = 0; i < 8; ++i) ohi[i] = lt[(dc0 + 8 + i) * 65 + pp];
    u16* out = WhT1 + (size_t)(c0t + pp) * Dd + r0 + dc0;
    *(u16x8*)(out)     = olo;
    *(u16x8*)(out + 8) = ohi;
  } else {
    const int idx = ((bid - 2048 - 32) * 256 + t) * 8;
    float4 v0 = *(const float4*)(Wh2 + idx);
    float4 v1 = *(const float4*)(Wh2 + idx + 4);
    u16x8 o;
    o[0]=f2bf(v0.x); o[1]=f2bf(v0.y); o[2]=f2bf(v0.z); o[3]=f2bf(v0.w);
    o[4]=f2bf(v1.x); o[5]=f2bf(v1.y); o[6]=f2bf(v1.z); o[7]=f2bf(v1.w);
    *(u16x8*)(Wbf2 + idx) = o;
  }
}

// ====== k_gram: G_part[kc][b][256][256] (bf16) = XpT[b] @ XpT[b]^T K-slice, plain stores ===
__global__ __launch_bounds__(256) void k_gram(const u16* __restrict__ XpT, u16* __restrict__ G_part) {
  __shared__ __align__(16) u16 ldsA[3 * 128 * 32];
  __shared__ __align__(16) u16 ldsB[3 * 64 * 32];
  const int bid0 = blockIdx.x;
  const int bid = (bid0 & 7) * 64 + (bid0 >> 3);   // bijective: 512 = 8 XCD * 64
  const int kc = bid & 7;
  const int tn = (bid >> 3) & 3;
  const int tm = (bid >> 5) & 1;
  const int b  = bid >> 6;
  const u16* Ag = XpT + (size_t)(b * Dd + tm * 128) * Nn;
  const u16* Bg = XpT + (size_t)(b * Dd + tn * 64) * Nn;
  f32x4 acc[4][2];
  acc_zero<2>(acc);
  gemm_tile<2>(Ag, Nn, Bg, Nn, kc * 512, 16, ldsA, ldsB, acc);
  const int tid = threadIdx.x, wave = tid >> 6, lane = tid & 63;
  const int wr = wave >> 1, wc = wave & 1, lr = lane & 15, lq = lane >> 4;
  u16* base = G_part + (size_t)kc * (Bb * Dd * Dd) + (size_t)(b * Dd + tm * 128) * Dd + tn * 64;
#pragma unroll
  for (int m = 0; m < 4; ++m)
#pragma unroll
    for (int n = 0; n < 2; ++n)
#pragma unroll
      for (int j = 0; j < 4; ++j)
        base[(size_t)(wr * 64 + m * 16 + lq * 4 + j) * Dd + wc * 32 + n * 16 + lr] =
            f2bf(acc[m][n][j]);
}

// ==== k_gsum: 256 blocks: Gb = bf16(sum of 8 bf16 slabs) ====
__global__ __launch_bounds__(256) void k_gsum(const u16* __restrict__ G_part, u16* __restrict__ Gb) {
  const int e = (blockIdx.x * 256 + threadIdx.x) * 8;
  float a[8] = {0.f,0.f,0.f,0.f,0.f,0.f,0.f,0.f};
#pragma unroll
  for (int k = 0; k < 8; ++k) {
    u16x8 v = *(const u16x8*)(G_part + (size_t)k * (Bb * Dd * Dd) + e);
#pragma unroll
    for (int i = 0; i < 8; ++i) a[i] += bf2f(v[i]);
  }
  u16x8 o;
#pragma unroll
  for (int i = 0; i < 8; ++i) o[i] = f2bf(a[i]);
  *(u16x8*)(Gb + e) = o;
}

// ==== k_pmAT: 128 blocks (NT=2): AT[b][d][p] = bf16(gelu(Wh1^T G + bh1 ⊗ s)); c_part ======
__global__ __launch_bounds__(256) void k_pmAT(const u16* __restrict__ WhT1, const u16* __restrict__ Gb,
                                              const float* __restrict__ s_part,
                                              const float* __restrict__ bh1, const float* __restrict__ bh2,
                                              u16* __restrict__ AT, float* __restrict__ c_part) {
  __shared__ __align__(16) u16 smem[18432];   // ldsA 3*4096 + ldsB 3*2048; ct (64*136) aliases
  __shared__ float sv[64];
  const int bid = blockIdx.x;        // 8b * 4tm(p) * 4tn(d64)
  const int tn = bid & 3;
  const int tm = (bid >> 2) & 3;
  const int b  = bid >> 4;
  const int p0 = tm * 128, d0 = tn * 64;
  const int tid = threadIdx.x;
  if (tid < 64) {
    float sum = 0.f;
#pragma unroll 8
    for (int nt = 0; nt < 64; ++nt) sum += s_part[(size_t)(b * 64 + nt) * Dd + d0 + tid];
    sv[tid] = sum;
  }
  u16* ldsA = smem;
  u16* ldsB = smem + 12288;
  f32x4 acc[4][2];
  acc_zero<2>(acc);
  gemm_tile<2>(WhT1 + (size_t)p0 * Dd, Dd, Gb + (size_t)(b * Dd + d0) * Dd, Dd,
               0, Dd / 32, ldsA, ldsB, acc);
  const int wave = tid >> 6, lane = tid & 63;
  const int wr = wave >> 1, wc = wave & 1, lr = lane & 15, lq = lane >> 4;
  u16* ct = smem;   // aliases gemm bufs (dead after trailing barrier)
#pragma unroll
  for (int n = 0; n < 2; ++n) {
    const int col = wc * 32 + n * 16 + lr;              // d local (0..63)
    const float svv = sv[col];
#pragma unroll
    for (int m = 0; m < 4; ++m)
#pragma unroll
      for (int j = 0; j < 4; ++j) {
        const int row = wr * 64 + m * 16 + lq * 4 + j;  // p local (0..127)
        ct[col * 136 + row] = f2bf(gelu_exact(acc[m][n][j] + bh1[p0 + row] * svv));
      }
  }
  __syncthreads();
#pragma unroll
  for (int it = 0; it < 4; ++it) {
    const int id = tid + it * 256;
    const int dl = id >> 4, ch = id & 15;
    *(u16x8*)(AT + (size_t)(b * Dd + d0 + dl) * DP + p0 + ch * 8) =
        *(const u16x8*)(ct + dl * 136 + ch * 8);
  }
  const int ccol = tid >> 2, qtr = tid & 3;
  float csum = 0.f;
#pragma unroll
  for (int q = 0; q < 4; ++q) {
    u16x8 av = *(const u16x8*)(ct + ccol * 136 + qtr * 32 + q * 8);
#pragma unroll
    for (int i = 0; i < 8; ++i) csum += bh2[p0 + qtr * 32 + q * 8 + i] * bf2f(av[i]);
  }
  csum += __shfl_xor(csum, 1);
  csum += __shfl_xor(csum, 2);
  if (qtr == 0) c_part[(size_t)(b * 4 + tm) * Dd + d0 + ccol] = csum;
}

// ---------------- k_h: 64 blocks (NT=2): HT[b][d_out][kd] = bf16(Wh2 @ A)^T ---------------
__global__ __launch_bounds__(256) void k_h(const u16* __restrict__ Wbf2, const u16* __restrict__ AT,
                                           u16* __restrict__ HT) {
  __shared__ __align__(16) u16 smem[18432];
  u16* ldsA = smem;
  u16* ldsB = smem + 12288;
  u16* ct   = smem;
  const int bid = blockIdx.x;        // 8b * 2tm(kd) * 4tn(d64)
  const int tn = bid & 3;
  const int tm = (bid >> 2) & 1;
  const int b  = bid >> 3;
  const int k0 = tm * 128, d0 = tn * 64;
  f32x4 acc[4][2];
  acc_zero<2>(acc);
  gemm_tile<2>(Wbf2 + (size_t)k0 * DP, DP, AT + (size_t)(b * Dd + d0) * DP, DP,
               0, DP / 32, ldsA, ldsB, acc);
  const int tid = threadIdx.x, wave = tid >> 6, lane = tid & 63;
  const int wr = wave >> 1, wc = wave & 1, lr = lane & 15, lq = lane >> 4;
#pragma unroll
  for (int n = 0; n < 2; ++n) {
    const int col = wc * 32 + n * 16 + lr;              // d_out local (0..63)
#pragma unroll
    for (int m = 0; m < 4; ++m)
#pragma unroll
      for (int j = 0; j < 4; ++j)
        ct[col * 136 + wr * 64 + m * 16 + lq * 4 + j] = f2bf(acc[m][n][j]);
  }
  __syncthreads();
#pragma unroll
  for (int it = 0; it < 4; ++it) {
    const int id = tid + it * 256;
    const int dl = id >> 4, ch = id & 15;
    *(u16x8*)(HT + (size_t)(b * Dd + d0 + dl) * Dd + k0 + ch * 8) =
        *(const u16x8*)(ct + dl * 136 + ch * 8);
  }
}

// -------- k_y: Y[b][n][d] = Xp[b] @ H[b] + sum_tm c_part  (1024 blocks of 128x64, NT=2) ---
__global__ __launch_bounds__(256) void k_y(const u16* __restrict__ Xp, const u16* __restrict__ HT,
                                           const float* __restrict__ c_part, float* __restrict__ Y) {
  __shared__ __align__(16) u16 ldsA[3 * 128 * 32];
  __shared__ __align__(16) u16 ldsB[3 * 64 * 32];
  const int bid0 = blockIdx.x;
  const int bid = (bid0 & 7) * 128 + (bid0 >> 3);   // bijective: 1024 = 8 XCD * 128
  const int b  = bid >> 7;
  const int tm = (bid >> 2) & 31;
  const int tn = bid & 3;
  const u16* Ag = Xp + (size_t)(b * Nn + tm * 128) * Dd;
  const u16* Bg = HT + (size_t)(b * Dd + tn * 64) * Dd;
  f32x4 acc[4][2];
  acc_zero<2>(acc);
  gemm_tile<2>(Ag, Dd, Bg, Dd, 0, Dd / 32, ldsA, ldsB, acc);
  const int tid = threadIdx.x, wave = tid >> 6, lane = tid & 63;
  const int wr = wave >> 1, wc = wave & 1, lr = lane & 15, lq = lane >> 4;
  float* base = Y + (size_t)(b * Nn + tm * 128) * Dd + tn * 64;
#pragma unroll
  for (int n = 0; n < 2; ++n) {
    const int col = wc * 32 + n * 16 + lr;
    const int gcol = tn * 64 + col;
    const float cv = c_part[(size_t)(b * 4 + 0) * Dd + gcol] + c_part[(size_t)(b * 4 + 1) * Dd + gcol]
                   + c_part[(size_t)(b * 4 + 2) * Dd + gcol] + c_part[(size_t)(b * 4 + 3) * Dd + gcol];
#pragma unroll
    for (int m = 0; m < 4; ++m)
#pragma unroll
      for (int j = 0; j < 4; ++j)
        base[(size_t)(wr * 64 + m * 16 + lq * 4 + j) * Dd + col] = acc[m][n][j] + cv;
  }
}

// ---------------- launcher ----------------
extern "C" void kernel_launch(void* const* d_in, const int* in_sizes, int n_in,
                              void* d_out, int out_size, void* d_ws, size_t ws_size,
                              hipStream_t stream) {
  const float* X   = (const float*)d_in[0];
  const float* P   = (const float*)d_in[1];
  const float* Wh1 = (const float*)d_in[2];
  const float* bh1 = (const float*)d_in[3];
  const float* Wh2 = (const float*)d_in[4];
  const float* bh2 = (const float*)d_in[5];
  float* Y = (float*)d_out;
  char* ws = (char*)d_ws;

  // workspace layout (bytes)
  u16*   Xp     = (u16*)(ws);                     // 16,777,216
  u16*   XpT    = (u16*)(ws + 16777216);          // 16,777,216
  u16*   WhT1   = (u16*)(ws + 33554432);          //    262,144
  u16*   Wbf2   = (u16*)(ws + 33816576);          //    262,144
  u16*   G_part = (u16*)(ws + 34078720);          //  8,388,608  (8 bf16 split-K slabs)
  float* s_part = (float*)(ws + 42467328);        //    524,288
  float* c_part = (float*)(ws + 42991616);        //     32,768
  u16*   Gb     = (u16*)(ws + 43024384);          //  1,048,576
  u16*   AT     = (u16*)(ws + 44072960);          //  2,097,152
  u16*   HT     = (u16*)(ws + 46170112);          //  1,048,576
  const size_t WS_NEED = 47218688;
  if (ws_size < WS_NEED) return;

  k_s1  <<<2144, 256, 0, stream>>>(X, P, Wh1, Wh2, Xp, XpT, s_part, WhT1, Wbf2);
  k_gram<<<512,  256, 0, stream>>>(XpT, G_part);
  k_gsum<<<256,  256, 0, stream>>>(G_part, Gb);
  k_pmAT<<<128,  256, 0, stream>>>(WhT1, Gb, s_part, bh1, bh2, AT, c_part);
  k_h   <<<64,   256, 0, stream>>>(Wbf2, AT, HT);
  k_y   <<<1024, 256, 0, stream>>>(Xp, HT, c_part, Y);
}